// Round 1
// 729.018 us; speedup vs baseline: 1.1642x; 1.1642x over previous
//
#include <hip/hip_runtime.h>
#include <math.h>

// ---------------------------------------------------------------------------
// StatusGCN restructured:
//   h0 = fp8e4m3(x @ W1)              (MFMA, fp32 A cast in staging) [N,256]
//   h1 = bf16(relu(spmm(h0) + b1))                                  [N,256]
//   g3 = bf16(h1 @ (W2@W3))           (MFMA)                        [N,64]
//   t1 = bf16(spmm(g3)); degw = rowsum(w)                           [N,64]
//   out = log_softmax(spmm(t1) + degw*(b2@W3) + r)                  [N,64] f32
// Identities: spmm(X)@W == spmm(X@W);  spmm(X + 1*c) == spmm(X) + degw*c.
// CSR build (r6 post-mortem): direct 8B random scatter had 8.7x write amp.
// 2-phase bucket sort instead:
//   pass1: LDS tile-sort by dst>>9 -> contiguous runs into bucket regions.
//   pass2: one block per bucket; LDS histogram + scan derives per-node
//          degrees AND cursors locally (writes rp), then exact placement.
// r7 (this round): per-node atomicAdd(&cnt[d],1) in pass1 was 3.2M
// device-scope far-atomics = ~102MB fabric WRITE traffic + the stall that
// held pass1 at 2.7% VALUBusy. Degree counting moved into pass2's LDS
// histogram (no global atomics); tb entries packed int4 -> int2
// (key = src<<9 | dst&511), halving scatter/place traffic; global scan
// kernels over N deleted (bucket-local scan + 256-entry gcnt scan suffice).
// NOTE (r4 post-mortem): keep per-wave MFMA tile at 64x64 (acc[4][4]=64 AGPR).
// acc[4][8] put wave reg total >256 on the unified VGPR/AGPR file -> 1
// wave/SIMD -> 9.5% occupancy. Widen the BLOCK (more waves), never the wave.
// ---------------------------------------------------------------------------

typedef __bf16 bf16x8 __attribute__((ext_vector_type(8)));
typedef __bf16 bf16x4 __attribute__((ext_vector_type(4)));
typedef float f32x4 __attribute__((ext_vector_type(4)));
typedef float f32x2 __attribute__((ext_vector_type(2)));

// ---------------- CSR construction (bucketed 2-phase) ----------------

#define TILE 2048

// pass 1: tile-sorted scatter into per-bucket regions (no per-node atomics)
__global__ __launch_bounds__(1024) void bucket_scatter(const int* __restrict__ src,
                                                       const int* __restrict__ dst,
                                                       const float* __restrict__ ew,
                                                       int* __restrict__ gcnt,
                                                       int2* __restrict__ tb,
                                                       int E, int buckcap) {
    __shared__ int hist[256];
    __shared__ int hscan[256];
    __shared__ int gbase[256];
    __shared__ int2 stage[TILE];
    __shared__ unsigned char sbuck[TILE];
    int tid = threadIdx.x;
    int e0 = blockIdx.x * TILE;
    int tilecnt = min(TILE, E - e0);
    if (tid < 256) hist[tid] = 0;
    __syncthreads();
    int myb[2], myr[2], key[2], mw[2];
#pragma unroll
    for (int u = 0; u < 2; ++u) {
        int e = e0 + u * 1024 + tid;
        myb[u] = -1;
        if (e < E) {
            int d = dst[e];
            int b = d >> 9;
            key[u] = (src[e] << 9) | (d & 511);
            mw[u] = __float_as_int(ew[e]);
            myb[u] = b;
            myr[u] = atomicAdd(&hist[b], 1);   // rank within (tile, bucket)
        }
    }
    __syncthreads();
    if (tid < 256) {
        hscan[tid] = hist[tid];
        gbase[tid] = (hist[tid] > 0) ? atomicAdd(&gcnt[tid], hist[tid]) : 0;
    }
    __syncthreads();
    for (int off = 1; off < 256; off <<= 1) {    // inclusive scan of hist
        int t = 0;
        if (tid < 256 && tid >= off) t = hscan[tid - off];
        __syncthreads();
        if (tid < 256) hscan[tid] += t;
        __syncthreads();
    }
#pragma unroll
    for (int u = 0; u < 2; ++u) {
        if (myb[u] >= 0) {
            int b = myb[u];
            int p = hscan[b] - hist[b] + myr[u];
            stage[p] = make_int2(key[u], mw[u]);
            sbuck[p] = (unsigned char)b;
        }
    }
    __syncthreads();
    for (int i = tid; i < tilecnt; i += 1024) {  // bursty, run-contiguous writes
        int2 ent = stage[i];
        int b = sbuck[i];
        int exc = hscan[b] - hist[b];
        tb[(size_t)b * buckcap + gbase[b] + (i - exc)] = ent;
    }
}

// exclusive scan of the 256 bucket totals -> bucket base offsets; rp[N]=E
__global__ __launch_bounds__(256) void gscan(const int* __restrict__ gcnt,
                                             int* __restrict__ boff,
                                             int* __restrict__ rp, int N, int E) {
    __shared__ int sd[256];
    int tid = threadIdx.x;
    int v = gcnt[tid];
    sd[tid] = v;
    __syncthreads();
    for (int off = 1; off < 256; off <<= 1) {
        int t = (tid >= off) ? sd[tid - off] : 0;
        __syncthreads();
        sd[tid] += t;
        __syncthreads();
    }
    boff[tid] = sd[tid] - v;
    if (tid == 0) rp[N] = E;
}

// pass 2: LDS histogram + scan -> per-node degrees, rp, and exact placement
__global__ __launch_bounds__(1024) void bucket_place(const int2* __restrict__ tb,
                                                     const int* __restrict__ gcnt,
                                                     const int* __restrict__ boff,
                                                     int* __restrict__ rp,
                                                     int2* __restrict__ ep,
                                                     int N, int buckcap) {
    __shared__ int h[512];
    __shared__ int cursor[512];
    int b = blockIdx.x;
    int base = b << 9;
    int nn = min(512, N - base);
    int tid = threadIdx.x;
    if (tid < 512) h[tid] = 0;
    __syncthreads();
    int cb = gcnt[b];
    const int2* tbb = tb + (size_t)b * buckcap;
    for (int i = tid; i < cb; i += 1024)
        atomicAdd(&h[((unsigned)tbb[i].x) & 511], 1);
    __syncthreads();
    if (tid < 512) cursor[tid] = h[tid];
    __syncthreads();
    for (int off = 1; off < 512; off <<= 1) {    // inclusive scan
        int t = (tid < 512 && tid >= off) ? cursor[tid - off] : 0;
        __syncthreads();
        if (tid < 512) cursor[tid] += t;
        __syncthreads();
    }
    int bo = boff[b];
    if (tid < 512) {
        int excl = cursor[tid] - h[tid] + bo;    // exclusive + bucket base
        cursor[tid] = excl;
        if (tid < nn) rp[base + tid] = excl;
    }
    __syncthreads();
    for (int i = tid; i < cb; i += 1024) {       // 2nd pass: L2-warm region
        int2 e = tbb[i];
        int pos = atomicAdd(&cursor[((unsigned)e.x) & 511], 1);
        ep[pos] = make_int2((int)(((unsigned)e.x) >> 9), e.y);
    }
}

// ---------------- tiny precomputes ----------------

__global__ __launch_bounds__(256) void cast_transpose(const float* __restrict__ W,
                                                      __bf16* __restrict__ WT,
                                                      int K, int Nn) {
    int i = blockIdx.x * 256 + threadIdx.x;
    if (i < K * Nn) {
        int k = i / Nn, n = i % Nn;
        WT[(size_t)n * K + k] = (__bf16)W[i];
    }
}

__global__ __launch_bounds__(256) void make_w23t(const float* __restrict__ W2,
                                                 const float* __restrict__ W3,
                                                 __bf16* __restrict__ W23T) {
    int idx = blockIdx.x * 256 + threadIdx.x;
    int n = idx & 63, k = idx >> 6;
    float s = 0.f;
    for (int j = 0; j < 64; ++j) s = fmaf(W2[k * 64 + j], W3[j * 64 + n], s);
    W23T[n * 256 + k] = (__bf16)s;
}

__global__ void make_c(const float* __restrict__ b2, const float* __restrict__ W3,
                       float* __restrict__ c) {
    int n = threadIdx.x;
    float s = 0.f;
    for (int j = 0; j < 64; ++j) s = fmaf(b2[j], W3[j * 64 + n], s);
    c[n] = s;
}

// ------- MFMA GEMM 1: h0_fp8[M,256] = bf16(A_f32[M,512]) @ W1[512,256] ------

__global__ __launch_bounds__(512) void gemm1_fused(const float* __restrict__ A,
                                                   const __bf16* __restrict__ BT,
                                                   unsigned char* __restrict__ C, int M) {
    const int K = 512;
    __shared__ __align__(16) __bf16 As[128 * 40];
    __shared__ __align__(16) __bf16 Bs[256 * 40];
    const int tid = threadIdx.x;
    const int wave = tid >> 6, lane = tid & 63;
    const int wm = wave >> 2, wn = wave & 3;
    const int quad = lane >> 4, l16 = lane & 15;
    const int bm = blockIdx.x * 128;
    f32x4 acc[4][4] = {};
    for (int k0 = 0; k0 < K; k0 += 32) {
#pragma unroll
        for (int it = 0; it < 2; ++it) {
            int idx = tid + it * 512;
            int row = idx >> 3, ch = idx & 7;
            int gm = bm + row;
            float4 v = (gm < M) ? *(const float4*)(A + (size_t)gm * K + k0 + ch * 4)
                                : make_float4(0.f, 0.f, 0.f, 0.f);
            bf16x4 o;
            o[0] = (__bf16)v.x; o[1] = (__bf16)v.y; o[2] = (__bf16)v.z; o[3] = (__bf16)v.w;
            *(bf16x4*)(As + row * 40 + ch * 4) = o;
        }
#pragma unroll
        for (int it = 0; it < 2; ++it) {
            int idx = tid + it * 512;
            int row = idx >> 2, ch = idx & 3;
            *(bf16x8*)(Bs + row * 40 + ch * 8) =
                *(const bf16x8*)(BT + (size_t)row * K + k0 + ch * 8);
        }
        __syncthreads();
        bf16x8 a[4], b[4];
#pragma unroll
        for (int i = 0; i < 4; ++i)
            a[i] = *(bf16x8*)(As + (wm * 64 + i * 16 + l16) * 40 + quad * 8);
#pragma unroll
        for (int j = 0; j < 4; ++j)
            b[j] = *(bf16x8*)(Bs + (wn * 64 + j * 16 + l16) * 40 + quad * 8);
#pragma unroll
        for (int i = 0; i < 4; ++i)
#pragma unroll
            for (int j = 0; j < 4; ++j)
                acc[i][j] = __builtin_amdgcn_mfma_f32_16x16x32_bf16(a[i], b[j], acc[i][j], 0, 0, 0);
        __syncthreads();
    }
#pragma unroll
    for (int i = 0; i < 4; ++i)
#pragma unroll
        for (int j = 0; j < 4; ++j)
#pragma unroll
            for (int rr = 0; rr < 4; ++rr) {
                int row = bm + wm * 64 + i * 16 + quad * 4 + rr;
                int col = wn * 64 + j * 16 + l16;
                if (row < M) {
                    unsigned int p = __builtin_amdgcn_cvt_pk_fp8_f32(acc[i][j][rr],
                                                                     acc[i][j][rr], 0, false);
                    C[(size_t)row * 256 + col] = (unsigned char)(p & 0xff);
                }
            }
}

// ---------------- MFMA GEMM 2: C[M,64] = A[M,256] @ B[256,64] ---------------

__global__ __launch_bounds__(256) void gemm2_mfma(const __bf16* __restrict__ A,
                                                  const __bf16* __restrict__ BT,
                                                  __bf16* __restrict__ C, int M) {
    const int K = 256, Nn = 64;
    __shared__ __align__(16) __bf16 Bs[64 * 264];
    __shared__ __align__(16) __bf16 As[128 * 40];
    const int tid = threadIdx.x;
    const int wave = tid >> 6, lane = tid & 63;
    const int quad = lane >> 4, l16 = lane & 15;
    const int bm = blockIdx.x * 128;
#pragma unroll
    for (int it = 0; it < 8; ++it) {
        int e = tid + it * 256;
        int row = e >> 5, ch = e & 31;
        *(bf16x8*)(Bs + row * 264 + ch * 8) = *(const bf16x8*)(BT + row * 256 + ch * 8);
    }
    f32x4 acc[2][4] = {};
    for (int k0 = 0; k0 < K; k0 += 32) {
#pragma unroll
        for (int it = 0; it < 2; ++it) {
            int e = tid + it * 256;
            int row = e >> 2, ch = e & 3;
            int gm = bm + row;
            bf16x8 v = {};
            if (gm < M) v = *(const bf16x8*)(A + (size_t)gm * K + k0 + ch * 8);
            *(bf16x8*)(As + row * 40 + ch * 8) = v;
        }
        __syncthreads();
        bf16x8 a[2], b[4];
#pragma unroll
        for (int i = 0; i < 2; ++i)
            a[i] = *(bf16x8*)(As + (wave * 32 + i * 16 + l16) * 40 + quad * 8);
#pragma unroll
        for (int j = 0; j < 4; ++j)
            b[j] = *(bf16x8*)(Bs + (j * 16 + l16) * 264 + k0 + quad * 8);
#pragma unroll
        for (int i = 0; i < 2; ++i)
#pragma unroll
            for (int j = 0; j < 4; ++j)
                acc[i][j] = __builtin_amdgcn_mfma_f32_16x16x32_bf16(a[i], b[j], acc[i][j], 0, 0, 0);
        __syncthreads();
    }
#pragma unroll
    for (int i = 0; i < 2; ++i)
#pragma unroll
        for (int j = 0; j < 4; ++j)
#pragma unroll
            for (int rr = 0; rr < 4; ++rr) {
                int row = bm + wave * 32 + i * 16 + quad * 4 + rr;
                int col = j * 16 + l16;
                if (row < M) C[(size_t)row * Nn + col] = (__bf16)acc[i][j][rr];
            }
}

// ---------------- pull-mode SpMM ----------------

__global__ __launch_bounds__(256) void spmm256_fp8(const unsigned char* __restrict__ h,
                                                   const int* __restrict__ rp,
                                                   const int2* __restrict__ ep,
                                                   const float* __restrict__ bias,
                                                   __bf16* __restrict__ out, int n) {
    int node = blockIdx.x * 4 + (threadIdx.x >> 6);
    if (node >= n) return;
    int lane = threadIdx.x & 63;
    int half = lane >> 5, c = lane & 31;
    int e0 = rp[node], e1 = rp[node + 1];
    float acc[8] = {};
    for (int e = e0; e < e1; e += 8) {
#pragma unroll
        for (int u = 0; u < 4; ++u) {
            int ee = e + u * 2 + half;
            int cl = min(ee, e1 - 1);
            int2 p = ep[cl];
            float w = (ee < e1) ? __int_as_float(p.y) : 0.f;
            uint2 v = *(const uint2*)(h + (size_t)p.x * 256 + c * 8);
            f32x2 f0 = __builtin_amdgcn_cvt_pk_f32_fp8(v.x, false);
            f32x2 f1 = __builtin_amdgcn_cvt_pk_f32_fp8(v.x, true);
            f32x2 f2 = __builtin_amdgcn_cvt_pk_f32_fp8(v.y, false);
            f32x2 f3 = __builtin_amdgcn_cvt_pk_f32_fp8(v.y, true);
            acc[0] = fmaf(w, f0.x, acc[0]); acc[1] = fmaf(w, f0.y, acc[1]);
            acc[2] = fmaf(w, f1.x, acc[2]); acc[3] = fmaf(w, f1.y, acc[3]);
            acc[4] = fmaf(w, f2.x, acc[4]); acc[5] = fmaf(w, f2.y, acc[5]);
            acc[6] = fmaf(w, f3.x, acc[6]); acc[7] = fmaf(w, f3.y, acc[7]);
        }
    }
#pragma unroll
    for (int i = 0; i < 8; ++i) acc[i] += __shfl_xor(acc[i], 32);
    if (half == 0) {
        float4 b0 = *(const float4*)(bias + c * 8);
        float4 b1 = *(const float4*)(bias + c * 8 + 4);
        bf16x8 o;
        o[0] = (__bf16)fmaxf(acc[0] + b0.x, 0.f);
        o[1] = (__bf16)fmaxf(acc[1] + b0.y, 0.f);
        o[2] = (__bf16)fmaxf(acc[2] + b0.z, 0.f);
        o[3] = (__bf16)fmaxf(acc[3] + b0.w, 0.f);
        o[4] = (__bf16)fmaxf(acc[4] + b1.x, 0.f);
        o[5] = (__bf16)fmaxf(acc[5] + b1.y, 0.f);
        o[6] = (__bf16)fmaxf(acc[6] + b1.z, 0.f);
        o[7] = (__bf16)fmaxf(acc[7] + b1.w, 0.f);
        *(bf16x8*)(out + (size_t)node * 256 + c * 8) = o;
    }
}

__global__ __launch_bounds__(256) void spmm64_a(const __bf16* __restrict__ h,
                                                const int* __restrict__ rp,
                                                const int2* __restrict__ ep,
                                                __bf16* __restrict__ out,
                                                float* __restrict__ degw, int n) {
    int node = blockIdx.x * 4 + (threadIdx.x >> 6);
    if (node >= n) return;
    int lane = threadIdx.x & 63;
    int g = lane >> 3, c = lane & 7;
    int e0 = rp[node], e1 = rp[node + 1];
    float acc[8] = {};
    float ws = 0.f;
    for (int e = e0; e < e1; e += 16) {
#pragma unroll
        for (int u = 0; u < 2; ++u) {
            int ee = e + u * 8 + g;
            int cl = min(ee, e1 - 1);
            int2 p = ep[cl];
            float w = (ee < e1) ? __int_as_float(p.y) : 0.f;
            bf16x8 v = *(const bf16x8*)(h + (size_t)p.x * 64 + c * 8);
#pragma unroll
            for (int i = 0; i < 8; ++i) acc[i] = fmaf(w, (float)v[i], acc[i]);
            ws += w;
        }
    }
#pragma unroll
    for (int off = 8; off <= 32; off <<= 1) {
        ws += __shfl_xor(ws, off);
#pragma unroll
        for (int i = 0; i < 8; ++i) acc[i] += __shfl_xor(acc[i], off);
    }
    if (lane == 0) degw[node] = ws;
    if (g == 0) {
        bf16x8 o;
#pragma unroll
        for (int i = 0; i < 8; ++i) o[i] = (__bf16)acc[i];
        *(bf16x8*)(out + (size_t)node * 64 + c * 8) = o;
    }
}

__global__ __launch_bounds__(256) void spmm64_b(const __bf16* __restrict__ h,
                                                const int* __restrict__ rp,
                                                const int2* __restrict__ ep,
                                                const float* __restrict__ degw,
                                                const float* __restrict__ cvec,
                                                const float* __restrict__ r,
                                                float* __restrict__ out, int n) {
    int node = blockIdx.x * 4 + (threadIdx.x >> 6);
    if (node >= n) return;
    int lane = threadIdx.x & 63;
    int g = lane >> 3, c = lane & 7;
    int e0 = rp[node], e1 = rp[node + 1];
    float acc[8] = {};
    for (int e = e0; e < e1; e += 16) {
#pragma unroll
        for (int u = 0; u < 2; ++u) {
            int ee = e + u * 8 + g;
            int cl = min(ee, e1 - 1);
            int2 p = ep[cl];
            float w = (ee < e1) ? __int_as_float(p.y) : 0.f;
            bf16x8 v = *(const bf16x8*)(h + (size_t)p.x * 64 + c * 8);
#pragma unroll
            for (int i = 0; i < 8; ++i) acc[i] = fmaf(w, (float)v[i], acc[i]);
        }
    }
#pragma unroll
    for (int off = 8; off <= 32; off <<= 1)
#pragma unroll
        for (int i = 0; i < 8; ++i) acc[i] += __shfl_xor(acc[i], off);
    float dw = degw[node];
    float4 c0 = *(const float4*)(cvec + c * 8), c1 = *(const float4*)(cvec + c * 8 + 4);
    float4 r0 = *(const float4*)(r + c * 8),    r1 = *(const float4*)(r + c * 8 + 4);
    float v[8];
    v[0] = acc[0] + dw * c0.x + r0.x; v[1] = acc[1] + dw * c0.y + r0.y;
    v[2] = acc[2] + dw * c0.z + r0.z; v[3] = acc[3] + dw * c0.w + r0.w;
    v[4] = acc[4] + dw * c1.x + r1.x; v[5] = acc[5] + dw * c1.y + r1.y;
    v[6] = acc[6] + dw * c1.z + r1.z; v[7] = acc[7] + dw * c1.w + r1.w;
    float m = v[0];
#pragma unroll
    for (int i = 1; i < 8; ++i) m = fmaxf(m, v[i]);
#pragma unroll
    for (int off = 1; off <= 4; off <<= 1) m = fmaxf(m, __shfl_xor(m, off));
    float s = 0.f;
#pragma unroll
    for (int i = 0; i < 8; ++i) s += __expf(v[i] - m);
#pragma unroll
    for (int off = 1; off <= 4; off <<= 1) s += __shfl_xor(s, off);
    float ls = m + __logf(s);
    if (g == 0) {
        float4 o0 = make_float4(v[0] - ls, v[1] - ls, v[2] - ls, v[3] - ls);
        float4 o1 = make_float4(v[4] - ls, v[5] - ls, v[6] - ls, v[7] - ls);
        *(float4*)(out + (size_t)node * 64 + c * 8) = o0;
        *(float4*)(out + (size_t)node * 64 + c * 8 + 4) = o1;
    }
}

// ---------------------------------------------------------------------------

extern "C" void kernel_launch(void* const* d_in, const int* in_sizes, int n_in,
                              void* d_out, int out_size, void* d_ws, size_t ws_size,
                              hipStream_t stream) {
    const float* x   = (const float*)d_in[0];
    const int*   src = (const int*)d_in[1];
    const int*   dst = (const int*)d_in[2];
    const float* ew  = (const float*)d_in[3];
    const float* W1  = (const float*)d_in[4];
    const float* b1  = (const float*)d_in[5];
    const float* W2  = (const float*)d_in[6];
    const float* b2  = (const float*)d_in[7];
    const float* W3  = (const float*)d_in[8];
    const float* r   = (const float*)d_in[9];

    const int N = in_sizes[0] / 512;       // 100000
    const int E = in_sizes[1];             // 3200000
    const int NB = (N + 511) >> 9;         // dst buckets (196)
    const int buckcap = (((E / NB) * 5) / 4 + 255) & ~255;   // ~20480

    // ---- workspace layout ----
    char* ws = (char*)d_ws;
    __bf16* h1 = (__bf16*)ws;                            // N*256 bf16 @ 0
    char* regB = ws + (size_t)N * 512;
    unsigned char* h0f = (unsigned char*)regB;           // N*256 fp8
    __bf16* g3   = (__bf16*)regB;                        // reuse after spmm256
    __bf16* t1   = (__bf16*)(regB + (size_t)N * 128);
    float*  degw = (float*)(regB + (size_t)N * 256);
    char* regC = regB + (size_t)N * 512;
    __bf16* W1T  = (__bf16*)regC;                        // 512*256 bf16
    __bf16* W23T = (__bf16*)(regC + 512 * 256 * 2);      // 64*256 bf16
    float*  cvec = (float*)(regC + 512 * 256 * 2 + 64 * 256 * 2);
    char* regD = regC + 512 * 1024;
    int*  rp   = (int*)regD;                             // N+1 (pad to N+2)
    int*  gcnt = rp + (N + 2);                           // 256 (zeroed)
    int*  boff = gcnt + 256;                             // 256 bucket bases
    int2* ep   = (int2*)(boff + 256);                    // E pairs (8B aligned)
    int2* tb   = ep + E;                                 // NB*buckcap entries

    // ---- CSR build (2-phase bucket sort, no per-node global atomics) ----
    hipMemsetAsync(gcnt, 0, 256 * sizeof(int), stream);
    bucket_scatter<<<(E + TILE - 1) / TILE, 1024, 0, stream>>>(src, dst, ew,
                                                               gcnt, tb, E, buckcap);
    gscan<<<1, 256, 0, stream>>>(gcnt, boff, rp, N, E);
    bucket_place<<<NB, 1024, 0, stream>>>(tb, gcnt, boff, rp, ep, N, buckcap);

    // ---- precomputes ----
    cast_transpose<<<(512 * 256 + 255) / 256, 256, 0, stream>>>(W1, W1T, 512, 256);
    make_w23t<<<64, 256, 0, stream>>>(W2, W3, W23T);
    make_c<<<1, 64, 0, stream>>>(b2, W3, cvec);

    // ---- layer 1 ----
    gemm1_fused<<<(N + 127) / 128, 512, 0, stream>>>(x, W1T, h0f, N);
    spmm256_fp8<<<(N + 3) / 4, 256, 0, stream>>>(h0f, rp, ep, b1, h1, N);

    // ---- fused layers 2+3 ----
    gemm2_mfma<<<(N + 127) / 128, 256, 0, stream>>>(h1, W23T, g3, N);
    spmm64_a<<<(N + 3) / 4, 256, 0, stream>>>(g3, rp, ep, t1, degw, N);
    spmm64_b<<<(N + 3) / 4, 256, 0, stream>>>(t1, rp, ep, degw, cvec, r, (float*)d_out, N);
}

// Round 2
// 707.566 us; speedup vs baseline: 1.1995x; 1.0303x over previous
//
#include <hip/hip_runtime.h>
#include <math.h>

// ---------------------------------------------------------------------------
// StatusGCN restructured:
//   h0 = fp8e4m3(x @ W1)              (MFMA, fp32 A cast in staging) [N,256]
//   h1 = bf16(relu(spmm(h0) + b1))                                  [N,256]
//   g3 = bf16(h1 @ (W2@W3))           (MFMA)                        [N,64]
//   t1 = bf16(spmm(g3)); degw = rowsum(w)                           [N,64]
//   out = log_softmax(spmm(t1) + degw*(b2@W3) + r)                  [N,64] f32
// Identities: spmm(X)@W == spmm(X@W);  spmm(X + 1*c) == spmm(X) + degw*c.
// CSR build: 2-phase bucket sort (pass1 LDS tile-sort -> bucket regions;
// pass2 per-bucket LDS histogram+scan writes rp and places exactly).
// r7 post-mortem: removing the 3.2M per-node far-atomics + int2 packing
// took bucket_scatter off the top-5 (total 849->729us). Theory confirmed.
// r8 (this round): spmm256_fp8 at 153us showed the latency-bound signature
// (BW 34%, VALU 41%, occ 77% -- nothing saturated). MLP was 8 edges/wave
// at 8B/lane. Now 4 edges/wave via uint4 (16B/lane, 16 lanes x 16B = same
// coalesced 256B row) x 4-unroll = 16 edges in flight; spmm64_* unroll 2->4.
// Same bytes, ~4x outstanding traffic per wave.
// NOTE (r4 post-mortem): keep per-wave MFMA tile at 64x64 (acc[4][4]=64 AGPR).
// acc[4][8] put wave reg total >256 on the unified VGPR/AGPR file -> 1
// wave/SIMD -> 9.5% occupancy. Widen the BLOCK (more waves), never the wave.
// ---------------------------------------------------------------------------

typedef __bf16 bf16x8 __attribute__((ext_vector_type(8)));
typedef __bf16 bf16x4 __attribute__((ext_vector_type(4)));
typedef float f32x4 __attribute__((ext_vector_type(4)));
typedef float f32x2 __attribute__((ext_vector_type(2)));

// ---------------- CSR construction (bucketed 2-phase) ----------------

#define TILE 2048

// pass 1: tile-sorted scatter into per-bucket regions (no per-node atomics)
__global__ __launch_bounds__(1024) void bucket_scatter(const int* __restrict__ src,
                                                       const int* __restrict__ dst,
                                                       const float* __restrict__ ew,
                                                       int* __restrict__ gcnt,
                                                       int2* __restrict__ tb,
                                                       int E, int buckcap) {
    __shared__ int hist[256];
    __shared__ int hscan[256];
    __shared__ int gbase[256];
    __shared__ int2 stage[TILE];
    __shared__ unsigned char sbuck[TILE];
    int tid = threadIdx.x;
    int e0 = blockIdx.x * TILE;
    int tilecnt = min(TILE, E - e0);
    if (tid < 256) hist[tid] = 0;
    __syncthreads();
    int myb[2], myr[2], key[2], mw[2];
#pragma unroll
    for (int u = 0; u < 2; ++u) {
        int e = e0 + u * 1024 + tid;
        myb[u] = -1;
        if (e < E) {
            int d = dst[e];
            int b = d >> 9;
            key[u] = (src[e] << 9) | (d & 511);
            mw[u] = __float_as_int(ew[e]);
            myb[u] = b;
            myr[u] = atomicAdd(&hist[b], 1);   // rank within (tile, bucket)
        }
    }
    __syncthreads();
    if (tid < 256) {
        hscan[tid] = hist[tid];
        gbase[tid] = (hist[tid] > 0) ? atomicAdd(&gcnt[tid], hist[tid]) : 0;
    }
    __syncthreads();
    for (int off = 1; off < 256; off <<= 1) {    // inclusive scan of hist
        int t = 0;
        if (tid < 256 && tid >= off) t = hscan[tid - off];
        __syncthreads();
        if (tid < 256) hscan[tid] += t;
        __syncthreads();
    }
#pragma unroll
    for (int u = 0; u < 2; ++u) {
        if (myb[u] >= 0) {
            int b = myb[u];
            int p = hscan[b] - hist[b] + myr[u];
            stage[p] = make_int2(key[u], mw[u]);
            sbuck[p] = (unsigned char)b;
        }
    }
    __syncthreads();
    for (int i = tid; i < tilecnt; i += 1024) {  // bursty, run-contiguous writes
        int2 ent = stage[i];
        int b = sbuck[i];
        int exc = hscan[b] - hist[b];
        tb[(size_t)b * buckcap + gbase[b] + (i - exc)] = ent;
    }
}

// exclusive scan of the 256 bucket totals -> bucket base offsets; rp[N]=E
__global__ __launch_bounds__(256) void gscan(const int* __restrict__ gcnt,
                                             int* __restrict__ boff,
                                             int* __restrict__ rp, int N, int E) {
    __shared__ int sd[256];
    int tid = threadIdx.x;
    int v = gcnt[tid];
    sd[tid] = v;
    __syncthreads();
    for (int off = 1; off < 256; off <<= 1) {
        int t = (tid >= off) ? sd[tid - off] : 0;
        __syncthreads();
        sd[tid] += t;
        __syncthreads();
    }
    boff[tid] = sd[tid] - v;
    if (tid == 0) rp[N] = E;
}

// pass 2: LDS histogram + scan -> per-node degrees, rp, and exact placement
__global__ __launch_bounds__(1024) void bucket_place(const int2* __restrict__ tb,
                                                     const int* __restrict__ gcnt,
                                                     const int* __restrict__ boff,
                                                     int* __restrict__ rp,
                                                     int2* __restrict__ ep,
                                                     int N, int buckcap) {
    __shared__ int h[512];
    __shared__ int cursor[512];
    int b = blockIdx.x;
    int base = b << 9;
    int nn = min(512, N - base);
    int tid = threadIdx.x;
    if (tid < 512) h[tid] = 0;
    __syncthreads();
    int cb = gcnt[b];
    const int2* tbb = tb + (size_t)b * buckcap;
    for (int i = tid; i < cb; i += 1024)
        atomicAdd(&h[((unsigned)tbb[i].x) & 511], 1);
    __syncthreads();
    if (tid < 512) cursor[tid] = h[tid];
    __syncthreads();
    for (int off = 1; off < 512; off <<= 1) {    // inclusive scan
        int t = (tid < 512 && tid >= off) ? cursor[tid - off] : 0;
        __syncthreads();
        if (tid < 512) cursor[tid] += t;
        __syncthreads();
    }
    int bo = boff[b];
    if (tid < 512) {
        int excl = cursor[tid] - h[tid] + bo;    // exclusive + bucket base
        cursor[tid] = excl;
        if (tid < nn) rp[base + tid] = excl;
    }
    __syncthreads();
    for (int i = tid; i < cb; i += 1024) {       // 2nd pass: L2-warm region
        int2 e = tbb[i];
        int pos = atomicAdd(&cursor[((unsigned)e.x) & 511], 1);
        ep[pos] = make_int2((int)(((unsigned)e.x) >> 9), e.y);
    }
}

// ---------------- tiny precomputes ----------------

__global__ __launch_bounds__(256) void cast_transpose(const float* __restrict__ W,
                                                      __bf16* __restrict__ WT,
                                                      int K, int Nn) {
    int i = blockIdx.x * 256 + threadIdx.x;
    if (i < K * Nn) {
        int k = i / Nn, n = i % Nn;
        WT[(size_t)n * K + k] = (__bf16)W[i];
    }
}

__global__ __launch_bounds__(256) void make_w23t(const float* __restrict__ W2,
                                                 const float* __restrict__ W3,
                                                 __bf16* __restrict__ W23T) {
    int idx = blockIdx.x * 256 + threadIdx.x;
    int n = idx & 63, k = idx >> 6;
    float s = 0.f;
    for (int j = 0; j < 64; ++j) s = fmaf(W2[k * 64 + j], W3[j * 64 + n], s);
    W23T[n * 256 + k] = (__bf16)s;
}

__global__ void make_c(const float* __restrict__ b2, const float* __restrict__ W3,
                       float* __restrict__ c) {
    int n = threadIdx.x;
    float s = 0.f;
    for (int j = 0; j < 64; ++j) s = fmaf(b2[j], W3[j * 64 + n], s);
    c[n] = s;
}

// ------- MFMA GEMM 1: h0_fp8[M,256] = bf16(A_f32[M,512]) @ W1[512,256] ------

__global__ __launch_bounds__(512) void gemm1_fused(const float* __restrict__ A,
                                                   const __bf16* __restrict__ BT,
                                                   unsigned char* __restrict__ C, int M) {
    const int K = 512;
    __shared__ __align__(16) __bf16 As[128 * 40];
    __shared__ __align__(16) __bf16 Bs[256 * 40];
    const int tid = threadIdx.x;
    const int wave = tid >> 6, lane = tid & 63;
    const int wm = wave >> 2, wn = wave & 3;
    const int quad = lane >> 4, l16 = lane & 15;
    const int bm = blockIdx.x * 128;
    f32x4 acc[4][4] = {};
    for (int k0 = 0; k0 < K; k0 += 32) {
#pragma unroll
        for (int it = 0; it < 2; ++it) {
            int idx = tid + it * 512;
            int row = idx >> 3, ch = idx & 7;
            int gm = bm + row;
            float4 v = (gm < M) ? *(const float4*)(A + (size_t)gm * K + k0 + ch * 4)
                                : make_float4(0.f, 0.f, 0.f, 0.f);
            bf16x4 o;
            o[0] = (__bf16)v.x; o[1] = (__bf16)v.y; o[2] = (__bf16)v.z; o[3] = (__bf16)v.w;
            *(bf16x4*)(As + row * 40 + ch * 4) = o;
        }
#pragma unroll
        for (int it = 0; it < 2; ++it) {
            int idx = tid + it * 512;
            int row = idx >> 2, ch = idx & 3;
            *(bf16x8*)(Bs + row * 40 + ch * 8) =
                *(const bf16x8*)(BT + (size_t)row * K + k0 + ch * 8);
        }
        __syncthreads();
        bf16x8 a[4], b[4];
#pragma unroll
        for (int i = 0; i < 4; ++i)
            a[i] = *(bf16x8*)(As + (wm * 64 + i * 16 + l16) * 40 + quad * 8);
#pragma unroll
        for (int j = 0; j < 4; ++j)
            b[j] = *(bf16x8*)(Bs + (wn * 64 + j * 16 + l16) * 40 + quad * 8);
#pragma unroll
        for (int i = 0; i < 4; ++i)
#pragma unroll
            for (int j = 0; j < 4; ++j)
                acc[i][j] = __builtin_amdgcn_mfma_f32_16x16x32_bf16(a[i], b[j], acc[i][j], 0, 0, 0);
        __syncthreads();
    }
#pragma unroll
    for (int i = 0; i < 4; ++i)
#pragma unroll
        for (int j = 0; j < 4; ++j)
#pragma unroll
            for (int rr = 0; rr < 4; ++rr) {
                int row = bm + wm * 64 + i * 16 + quad * 4 + rr;
                int col = wn * 64 + j * 16 + l16;
                if (row < M) {
                    unsigned int p = __builtin_amdgcn_cvt_pk_fp8_f32(acc[i][j][rr],
                                                                     acc[i][j][rr], 0, false);
                    C[(size_t)row * 256 + col] = (unsigned char)(p & 0xff);
                }
            }
}

// ---------------- MFMA GEMM 2: C[M,64] = A[M,256] @ B[256,64] ---------------

__global__ __launch_bounds__(256) void gemm2_mfma(const __bf16* __restrict__ A,
                                                  const __bf16* __restrict__ BT,
                                                  __bf16* __restrict__ C, int M) {
    const int K = 256, Nn = 64;
    __shared__ __align__(16) __bf16 Bs[64 * 264];
    __shared__ __align__(16) __bf16 As[128 * 40];
    const int tid = threadIdx.x;
    const int wave = tid >> 6, lane = tid & 63;
    const int quad = lane >> 4, l16 = lane & 15;
    const int bm = blockIdx.x * 128;
#pragma unroll
    for (int it = 0; it < 8; ++it) {
        int e = tid + it * 256;
        int row = e >> 5, ch = e & 31;
        *(bf16x8*)(Bs + row * 264 + ch * 8) = *(const bf16x8*)(BT + row * 256 + ch * 8);
    }
    f32x4 acc[2][4] = {};
    for (int k0 = 0; k0 < K; k0 += 32) {
#pragma unroll
        for (int it = 0; it < 2; ++it) {
            int e = tid + it * 256;
            int row = e >> 2, ch = e & 3;
            int gm = bm + row;
            bf16x8 v = {};
            if (gm < M) v = *(const bf16x8*)(A + (size_t)gm * K + k0 + ch * 8);
            *(bf16x8*)(As + row * 40 + ch * 8) = v;
        }
        __syncthreads();
        bf16x8 a[2], b[4];
#pragma unroll
        for (int i = 0; i < 2; ++i)
            a[i] = *(bf16x8*)(As + (wave * 32 + i * 16 + l16) * 40 + quad * 8);
#pragma unroll
        for (int j = 0; j < 4; ++j)
            b[j] = *(bf16x8*)(Bs + (j * 16 + l16) * 264 + k0 + quad * 8);
#pragma unroll
        for (int i = 0; i < 2; ++i)
#pragma unroll
            for (int j = 0; j < 4; ++j)
                acc[i][j] = __builtin_amdgcn_mfma_f32_16x16x32_bf16(a[i], b[j], acc[i][j], 0, 0, 0);
        __syncthreads();
    }
#pragma unroll
    for (int i = 0; i < 2; ++i)
#pragma unroll
        for (int j = 0; j < 4; ++j)
#pragma unroll
            for (int rr = 0; rr < 4; ++rr) {
                int row = bm + wave * 32 + i * 16 + quad * 4 + rr;
                int col = j * 16 + l16;
                if (row < M) C[(size_t)row * Nn + col] = (__bf16)acc[i][j][rr];
            }
}

// ---------------- pull-mode SpMM ----------------

// r8: 4 edges/wave concurrently (q = lane>>4), 16 lanes x uint4 = 256B row,
// 4-deep unroll -> 16 edges in flight, 64B/lane outstanding.
__global__ __launch_bounds__(256) void spmm256_fp8(const unsigned char* __restrict__ h,
                                                   const int* __restrict__ rp,
                                                   const int2* __restrict__ ep,
                                                   const float* __restrict__ bias,
                                                   __bf16* __restrict__ out, int n) {
    int node = blockIdx.x * 4 + (threadIdx.x >> 6);
    if (node >= n) return;
    int lane = threadIdx.x & 63;
    int q = lane >> 4, c = lane & 15;
    int e0 = rp[node], e1 = rp[node + 1];
    float acc[16] = {};
    for (int e = e0; e < e1; e += 16) {
#pragma unroll
        for (int u = 0; u < 4; ++u) {
            int ee = e + u * 4 + q;
            int cl = min(ee, e1 - 1);
            int2 p = ep[cl];
            float w = (ee < e1) ? __int_as_float(p.y) : 0.f;
            uint4 v = *(const uint4*)(h + (size_t)p.x * 256 + c * 16);
            f32x2 f;
            f = __builtin_amdgcn_cvt_pk_f32_fp8(v.x, false);
            acc[0] = fmaf(w, f.x, acc[0]);  acc[1] = fmaf(w, f.y, acc[1]);
            f = __builtin_amdgcn_cvt_pk_f32_fp8(v.x, true);
            acc[2] = fmaf(w, f.x, acc[2]);  acc[3] = fmaf(w, f.y, acc[3]);
            f = __builtin_amdgcn_cvt_pk_f32_fp8(v.y, false);
            acc[4] = fmaf(w, f.x, acc[4]);  acc[5] = fmaf(w, f.y, acc[5]);
            f = __builtin_amdgcn_cvt_pk_f32_fp8(v.y, true);
            acc[6] = fmaf(w, f.x, acc[6]);  acc[7] = fmaf(w, f.y, acc[7]);
            f = __builtin_amdgcn_cvt_pk_f32_fp8(v.z, false);
            acc[8] = fmaf(w, f.x, acc[8]);  acc[9] = fmaf(w, f.y, acc[9]);
            f = __builtin_amdgcn_cvt_pk_f32_fp8(v.z, true);
            acc[10] = fmaf(w, f.x, acc[10]); acc[11] = fmaf(w, f.y, acc[11]);
            f = __builtin_amdgcn_cvt_pk_f32_fp8(v.w, false);
            acc[12] = fmaf(w, f.x, acc[12]); acc[13] = fmaf(w, f.y, acc[13]);
            f = __builtin_amdgcn_cvt_pk_f32_fp8(v.w, true);
            acc[14] = fmaf(w, f.x, acc[14]); acc[15] = fmaf(w, f.y, acc[15]);
        }
    }
#pragma unroll
    for (int off = 16; off <= 32; off <<= 1)
#pragma unroll
        for (int i = 0; i < 16; ++i) acc[i] += __shfl_xor(acc[i], off);
    if (q == 0) {
        float4 b0 = *(const float4*)(bias + c * 16);
        float4 b1 = *(const float4*)(bias + c * 16 + 4);
        float4 b2 = *(const float4*)(bias + c * 16 + 8);
        float4 b3 = *(const float4*)(bias + c * 16 + 12);
        bf16x8 o0, o1;
        o0[0] = (__bf16)fmaxf(acc[0] + b0.x, 0.f);
        o0[1] = (__bf16)fmaxf(acc[1] + b0.y, 0.f);
        o0[2] = (__bf16)fmaxf(acc[2] + b0.z, 0.f);
        o0[3] = (__bf16)fmaxf(acc[3] + b0.w, 0.f);
        o0[4] = (__bf16)fmaxf(acc[4] + b1.x, 0.f);
        o0[5] = (__bf16)fmaxf(acc[5] + b1.y, 0.f);
        o0[6] = (__bf16)fmaxf(acc[6] + b1.z, 0.f);
        o0[7] = (__bf16)fmaxf(acc[7] + b1.w, 0.f);
        o1[0] = (__bf16)fmaxf(acc[8] + b2.x, 0.f);
        o1[1] = (__bf16)fmaxf(acc[9] + b2.y, 0.f);
        o1[2] = (__bf16)fmaxf(acc[10] + b2.z, 0.f);
        o1[3] = (__bf16)fmaxf(acc[11] + b2.w, 0.f);
        o1[4] = (__bf16)fmaxf(acc[12] + b3.x, 0.f);
        o1[5] = (__bf16)fmaxf(acc[13] + b3.y, 0.f);
        o1[6] = (__bf16)fmaxf(acc[14] + b3.z, 0.f);
        o1[7] = (__bf16)fmaxf(acc[15] + b3.w, 0.f);
        *(bf16x8*)(out + (size_t)node * 256 + c * 16) = o0;
        *(bf16x8*)(out + (size_t)node * 256 + c * 16 + 8) = o1;
    }
}

__global__ __launch_bounds__(256) void spmm64_a(const __bf16* __restrict__ h,
                                                const int* __restrict__ rp,
                                                const int2* __restrict__ ep,
                                                __bf16* __restrict__ out,
                                                float* __restrict__ degw, int n) {
    int node = blockIdx.x * 4 + (threadIdx.x >> 6);
    if (node >= n) return;
    int lane = threadIdx.x & 63;
    int g = lane >> 3, c = lane & 7;
    int e0 = rp[node], e1 = rp[node + 1];
    float acc[8] = {};
    float ws = 0.f;
    for (int e = e0; e < e1; e += 32) {
#pragma unroll
        for (int u = 0; u < 4; ++u) {
            int ee = e + u * 8 + g;
            int cl = min(ee, e1 - 1);
            int2 p = ep[cl];
            float w = (ee < e1) ? __int_as_float(p.y) : 0.f;
            bf16x8 v = *(const bf16x8*)(h + (size_t)p.x * 64 + c * 8);
#pragma unroll
            for (int i = 0; i < 8; ++i) acc[i] = fmaf(w, (float)v[i], acc[i]);
            ws += w;
        }
    }
#pragma unroll
    for (int off = 8; off <= 32; off <<= 1) {
        ws += __shfl_xor(ws, off);
#pragma unroll
        for (int i = 0; i < 8; ++i) acc[i] += __shfl_xor(acc[i], off);
    }
    if (lane == 0) degw[node] = ws;
    if (g == 0) {
        bf16x8 o;
#pragma unroll
        for (int i = 0; i < 8; ++i) o[i] = (__bf16)acc[i];
        *(bf16x8*)(out + (size_t)node * 64 + c * 8) = o;
    }
}

__global__ __launch_bounds__(256) void spmm64_b(const __bf16* __restrict__ h,
                                                const int* __restrict__ rp,
                                                const int2* __restrict__ ep,
                                                const float* __restrict__ degw,
                                                const float* __restrict__ cvec,
                                                const float* __restrict__ r,
                                                float* __restrict__ out, int n) {
    int node = blockIdx.x * 4 + (threadIdx.x >> 6);
    if (node >= n) return;
    int lane = threadIdx.x & 63;
    int g = lane >> 3, c = lane & 7;
    int e0 = rp[node], e1 = rp[node + 1];
    float acc[8] = {};
    for (int e = e0; e < e1; e += 32) {
#pragma unroll
        for (int u = 0; u < 4; ++u) {
            int ee = e + u * 8 + g;
            int cl = min(ee, e1 - 1);
            int2 p = ep[cl];
            float w = (ee < e1) ? __int_as_float(p.y) : 0.f;
            bf16x8 v = *(const bf16x8*)(h + (size_t)p.x * 64 + c * 8);
#pragma unroll
            for (int i = 0; i < 8; ++i) acc[i] = fmaf(w, (float)v[i], acc[i]);
        }
    }
#pragma unroll
    for (int off = 8; off <= 32; off <<= 1)
#pragma unroll
        for (int i = 0; i < 8; ++i) acc[i] += __shfl_xor(acc[i], off);
    float dw = degw[node];
    float4 c0 = *(const float4*)(cvec + c * 8), c1 = *(const float4*)(cvec + c * 8 + 4);
    float4 r0 = *(const float4*)(r + c * 8),    r1 = *(const float4*)(r + c * 8 + 4);
    float v[8];
    v[0] = acc[0] + dw * c0.x + r0.x; v[1] = acc[1] + dw * c0.y + r0.y;
    v[2] = acc[2] + dw * c0.z + r0.z; v[3] = acc[3] + dw * c0.w + r0.w;
    v[4] = acc[4] + dw * c1.x + r1.x; v[5] = acc[5] + dw * c1.y + r1.y;
    v[6] = acc[6] + dw * c1.z + r1.z; v[7] = acc[7] + dw * c1.w + r1.w;
    float m = v[0];
#pragma unroll
    for (int i = 1; i < 8; ++i) m = fmaxf(m, v[i]);
#pragma unroll
    for (int off = 1; off <= 4; off <<= 1) m = fmaxf(m, __shfl_xor(m, off));
    float s = 0.f;
#pragma unroll
    for (int i = 0; i < 8; ++i) s += __expf(v[i] - m);
#pragma unroll
    for (int off = 1; off <= 4; off <<= 1) s += __shfl_xor(s, off);
    float ls = m + __logf(s);
    if (g == 0) {
        float4 o0 = make_float4(v[0] - ls, v[1] - ls, v[2] - ls, v[3] - ls);
        float4 o1 = make_float4(v[4] - ls, v[5] - ls, v[6] - ls, v[7] - ls);
        *(float4*)(out + (size_t)node * 64 + c * 8) = o0;
        *(float4*)(out + (size_t)node * 64 + c * 8 + 4) = o1;
    }
}

// ---------------------------------------------------------------------------

extern "C" void kernel_launch(void* const* d_in, const int* in_sizes, int n_in,
                              void* d_out, int out_size, void* d_ws, size_t ws_size,
                              hipStream_t stream) {
    const float* x   = (const float*)d_in[0];
    const int*   src = (const int*)d_in[1];
    const int*   dst = (const int*)d_in[2];
    const float* ew  = (const float*)d_in[3];
    const float* W1  = (const float*)d_in[4];
    const float* b1  = (const float*)d_in[5];
    const float* W2  = (const float*)d_in[6];
    const float* b2  = (const float*)d_in[7];
    const float* W3  = (const float*)d_in[8];
    const float* r   = (const float*)d_in[9];

    const int N = in_sizes[0] / 512;       // 100000
    const int E = in_sizes[1];             // 3200000
    const int NB = (N + 511) >> 9;         // dst buckets (196)
    const int buckcap = (((E / NB) * 5) / 4 + 255) & ~255;   // ~20480

    // ---- workspace layout ----
    char* ws = (char*)d_ws;
    __bf16* h1 = (__bf16*)ws;                            // N*256 bf16 @ 0
    char* regB = ws + (size_t)N * 512;
    unsigned char* h0f = (unsigned char*)regB;           // N*256 fp8
    __bf16* g3   = (__bf16*)regB;                        // reuse after spmm256
    __bf16* t1   = (__bf16*)(regB + (size_t)N * 128);
    float*  degw = (float*)(regB + (size_t)N * 256);
    char* regC = regB + (size_t)N * 512;
    __bf16* W1T  = (__bf16*)regC;                        // 512*256 bf16
    __bf16* W23T = (__bf16*)(regC + 512 * 256 * 2);      // 64*256 bf16
    float*  cvec = (float*)(regC + 512 * 256 * 2 + 64 * 256 * 2);
    char* regD = regC + 512 * 1024;
    int*  rp   = (int*)regD;                             // N+1 (pad to N+2)
    int*  gcnt = rp + (N + 2);                           // 256 (zeroed)
    int*  boff = gcnt + 256;                             // 256 bucket bases
    int2* ep   = (int2*)(boff + 256);                    // E pairs (8B aligned)
    int2* tb   = ep + E;                                 // NB*buckcap entries

    // ---- CSR build (2-phase bucket sort, no per-node global atomics) ----
    hipMemsetAsync(gcnt, 0, 256 * sizeof(int), stream);
    bucket_scatter<<<(E + TILE - 1) / TILE, 1024, 0, stream>>>(src, dst, ew,
                                                               gcnt, tb, E, buckcap);
    gscan<<<1, 256, 0, stream>>>(gcnt, boff, rp, N, E);
    bucket_place<<<NB, 1024, 0, stream>>>(tb, gcnt, boff, rp, ep, N, buckcap);

    // ---- precomputes ----
    cast_transpose<<<(512 * 256 + 255) / 256, 256, 0, stream>>>(W1, W1T, 512, 256);
    make_w23t<<<64, 256, 0, stream>>>(W2, W3, W23T);
    make_c<<<1, 64, 0, stream>>>(b2, W3, cvec);

    // ---- layer 1 ----
    gemm1_fused<<<(N + 127) / 128, 512, 0, stream>>>(x, W1T, h0f, N);
    spmm256_fp8<<<(N + 3) / 4, 256, 0, stream>>>(h0f, rp, ep, b1, h1, N);

    // ---- fused layers 2+3 ----
    gemm2_mfma<<<(N + 127) / 128, 256, 0, stream>>>(h1, W23T, g3, N);
    spmm64_a<<<(N + 3) / 4, 256, 0, stream>>>(g3, rp, ep, t1, degw, N);
    spmm64_b<<<(N + 3) / 4, 256, 0, stream>>>(t1, rp, ep, degw, cvec, r, (float*)d_out, N);
}